// Round 1
// baseline (4528.875 us; speedup 1.0000x reference)
//
#include <hip/hip_runtime.h>

// ---------------------------------------------------------------------------
// VQ-VAE forward, fp32 correctness-first baseline.
// Outputs in d_out (float32, concatenated): y[6291456], loss[1], idx[32768]
// ---------------------------------------------------------------------------

// Generic direct conv, NHWC, HWIO weights.
// hi = ho*STR - PAD + r. Thread = (pixel-group, f). PPT pixels per thread.
template<int R,int S,int CIN,int COUT,int STR,int PAD,int BLK,int PPT,int ACT>
__global__ __launch_bounds__(BLK) void conv_fp32(
    const float* __restrict__ x, const float* __restrict__ w,
    const float* __restrict__ bias, float* __restrict__ y,
    int N, int Hin, int Win, int Hout, int Wout)
{
    constexpr int GPB = BLK / COUT;          // pixel-groups per block
    const int t = threadIdx.x;
    const int f = t % COUT;
    const int g = t / COUT;
    const int base = (blockIdx.x * GPB + g) * PPT;
    const int HW = Hout * Wout;

    int nn[PPT], ho[PPT], wo[PPT];
    float acc[PPT];
    const float bv = bias[f];
#pragma unroll
    for (int j = 0; j < PPT; ++j) {
        int p = base + j;
        nn[j] = p / HW;
        int rem = p - nn[j]*HW;
        ho[j] = rem / Wout;
        wo[j] = rem - ho[j]*Wout;
        acc[j] = bv;
    }
#pragma unroll
    for (int r = 0; r < R; ++r) {
#pragma unroll
        for (int s = 0; s < S; ++s) {
            const float* wp = w + ((r*S + s)*CIN)*COUT + f;
            int xoff[PPT]; bool v[PPT];
#pragma unroll
            for (int j = 0; j < PPT; ++j) {
                int hi = ho[j]*STR - PAD + r;
                int wi = wo[j]*STR - PAD + s;
                v[j] = (hi >= 0) && (hi < Hin) && (wi >= 0) && (wi < Win);
                xoff[j] = v[j] ? ((nn[j]*Hin + hi)*Win + wi)*CIN : 0;
            }
#pragma unroll 4
            for (int c = 0; c < CIN; ++c) {
                float wv = wp[c*COUT];
#pragma unroll
                for (int j = 0; j < PPT; ++j) {
                    float xv = v[j] ? x[xoff[j] + c] : 0.0f;
                    acc[j] = fmaf(xv, wv, acc[j]);
                }
            }
        }
    }
#pragma unroll
    for (int j = 0; j < PPT; ++j) {
        float o = acc[j];
        if (ACT == 1) o = fmaxf(o, 0.0f);
        if (ACT == 2) o = 1.0f / (1.0f + __expf(-o));
        y[(base + j)*COUT + f] = o;
    }
}

// conv_transpose, kernel 4x4, stride 2, SAME (pad_a=pad_b=2 on 2x-dilated input,
// kernel used as-is, HWIO). Output parity (ph,pw) selects 2x2 taps:
//   r = ph + 2*rr, xi = hh + ph - 1 + rr   (ho = 2*hh + ph), same for w dim.
// gridDim.y = 4 encodes parity so taps are block-uniform.
template<int CIN,int COUT,int BLK,int PPT,int ACT>
__global__ __launch_bounds__(BLK) void convt4x4s2(
    const float* __restrict__ x, const float* __restrict__ w,
    const float* __restrict__ bias, float* __restrict__ y,
    int N, int Hin, int Win)
{
    const int Hout = 2*Hin, Wout = 2*Win;
    const int ph = blockIdx.y >> 1, pw = blockIdx.y & 1;
    constexpr int GPB = BLK / COUT;
    const int t = threadIdx.x;
    const int f = t % COUT;
    const int g = t / COUT;
    const int base = (blockIdx.x * GPB + g) * PPT;   // sub-image pixel index
    const int HWs = Hin * Win;

    int nn[PPT], hh[PPT], wh[PPT];
    float acc[PPT];
    const float bv = bias[f];
#pragma unroll
    for (int j = 0; j < PPT; ++j) {
        int p = base + j;
        nn[j] = p / HWs;
        int rem = p - nn[j]*HWs;
        hh[j] = rem / Win;
        wh[j] = rem - hh[j]*Win;
        acc[j] = bv;
    }
#pragma unroll
    for (int rr = 0; rr < 2; ++rr) {
#pragma unroll
        for (int ss = 0; ss < 2; ++ss) {
            const int r = ph + 2*rr, s = pw + 2*ss;
            const float* wp = w + ((r*4 + s)*CIN)*COUT + f;
            int xoff[PPT]; bool v[PPT];
#pragma unroll
            for (int j = 0; j < PPT; ++j) {
                int xi = hh[j] + ph - 1 + rr;
                int yi = wh[j] + pw - 1 + ss;
                v[j] = (xi >= 0) && (xi < Hin) && (yi >= 0) && (yi < Win);
                xoff[j] = v[j] ? ((nn[j]*Hin + xi)*Win + yi)*CIN : 0;
            }
#pragma unroll 4
            for (int c = 0; c < CIN; ++c) {
                float wv = wp[c*COUT];
#pragma unroll
                for (int j = 0; j < PPT; ++j) {
                    float xv = v[j] ? x[xoff[j] + c] : 0.0f;
                    acc[j] = fmaf(xv, wv, acc[j]);
                }
            }
        }
    }
#pragma unroll
    for (int j = 0; j < PPT; ++j) {
        float o = acc[j];
        if (ACT == 1) o = fmaxf(o, 0.0f);
        if (ACT == 2) o = 1.0f / (1.0f + __expf(-o));
        int ho = 2*hh[j] + ph, wo = 2*wh[j] + pw;
        y[((nn[j]*Hout + ho)*Wout + wo)*COUT + f] = o;
    }
}

__global__ void zero_loss(float* p) {
    if (threadIdx.x == 0 && blockIdx.x == 0) *p = 0.0f;
}

// VQ: block = 64 positions x 4 code groups (group g scans codes == g mod 4).
// Direct fp32 ||z - e||^2, strict < ascending => np.argmin first-min semantics;
// cross-group merge ties -> lower index. best distance == sum (q-z)^2 -> loss.
__global__ __launch_bounds__(256) void vq_kernel(
    const float* __restrict__ z, const float* __restrict__ emb,
    float* __restrict__ q, float* __restrict__ idx_out,
    float* __restrict__ loss_out, float loss_scale)
{
    __shared__ float zs[64*65];     // +1 pad: reads zs[lane*65+d] are 2-way (free)
    __shared__ float es[64*64];     // emb chunk, broadcast reads
    __shared__ float gd[4*64];
    __shared__ int   gi[4*64];
    __shared__ float md[64];
    __shared__ int   mi[64];

    const int t = threadIdx.x;
    const int pos0 = blockIdx.x * 64;

    for (int j = t; j < 64*64; j += 256)
        zs[(j >> 6)*65 + (j & 63)] = z[pos0*64 + j];
    __syncthreads();

    const int pos = t & 63;
    const int grp = t >> 6;
    float zr[64];
#pragma unroll
    for (int d = 0; d < 64; ++d) zr[d] = zs[pos*65 + d];

    float bestd = 3.4e38f;
    int   besti = 0;

    for (int ck = 0; ck < 8; ++ck) {
        __syncthreads();
        for (int j = t; j < 4096; j += 256) es[j] = emb[ck*4096 + j];
        __syncthreads();
#pragma unroll
        for (int k = 0; k < 16; ++k) {
            const int cc = grp + 4*k;
            const float4* ep = (const float4*)(es + cc*64);
            float acc = 0.0f;
#pragma unroll
            for (int u = 0; u < 16; ++u) {
                float4 e = ep[u];
                float d0 = zr[4*u+0] - e.x;
                float d1 = zr[4*u+1] - e.y;
                float d2 = zr[4*u+2] - e.z;
                float d3 = zr[4*u+3] - e.w;
                acc = fmaf(d0,d0,acc); acc = fmaf(d1,d1,acc);
                acc = fmaf(d2,d2,acc); acc = fmaf(d3,d3,acc);
            }
            const int code = ck*64 + cc;
            if (acc < bestd) { bestd = acc; besti = code; }
        }
    }
    gd[grp*64 + pos] = bestd;
    gi[grp*64 + pos] = besti;
    __syncthreads();
    if (grp == 0) {
        float bd = gd[pos]; int bi = gi[pos];
#pragma unroll
        for (int g2 = 1; g2 < 4; ++g2) {
            float dv = gd[g2*64 + pos]; int iv = gi[g2*64 + pos];
            if (dv < bd || (dv == bd && iv < bi)) { bd = dv; bi = iv; }
        }
        md[pos] = bd; mi[pos] = bi;
        idx_out[pos0 + pos] = (float)bi;
    }
    __syncthreads();
    for (int j = t; j < 4096; j += 256) {
        int p = j >> 6, d = j & 63;
        q[pos0*64 + j] = emb[mi[p]*64 + d];
    }
    if (t == 0) {
        float s = 0.0f;
        for (int p = 0; p < 64; ++p) s += md[p];
        atomicAdd(loss_out, s * loss_scale);
    }
}

extern "C" void kernel_launch(void* const* d_in, const int* in_sizes, int n_in,
                              void* d_out, int out_size, void* d_ws, size_t ws_size,
                              hipStream_t stream)
{
    const float* x   = (const float*)d_in[0];
    const float* ew1 = (const float*)d_in[1];  const float* eb1 = (const float*)d_in[2];
    const float* ew2 = (const float*)d_in[3];  const float* eb2 = (const float*)d_in[4];
    const float* ew3 = (const float*)d_in[5];  const float* eb3 = (const float*)d_in[6];
    const float* ew4 = (const float*)d_in[7];  const float* eb4 = (const float*)d_in[8];
    const float* emb = (const float*)d_in[9];
    const float* dw1 = (const float*)d_in[10]; const float* db1 = (const float*)d_in[11];
    const float* dw2 = (const float*)d_in[12]; const float* db2 = (const float*)d_in[13];
    const float* dw3 = (const float*)d_in[14]; const float* db3 = (const float*)d_in[15];
    const float* dw4 = (const float*)d_in[16]; const float* db4 = (const float*)d_in[17];

    float* outy = (float*)d_out;          // y: 128*128*128*3 = 6291456
    float* outl = outy + 6291456;         // loss: 1
    float* outi = outl + 1;               // idx: 128*256 = 32768 (written as float)

    float* ws = (float*)d_ws;
    float* A  = ws;                // 16777216 floats (z1 / d3out)
    float* Bb = A  + 16777216;     //  8388608 floats (z2 / d2out)
    float* C  = Bb + 8388608;      //  4194304 floats (z3 / d1out)
    float* D  = C  + 4194304;      //  2097152 floats (z)
    float* E  = D  + 2097152;      //  2097152 floats (q)
    // total ws use: 134,217,728 bytes

    // ---- encoder ----
    hipLaunchKernelGGL((conv_fp32<4,4,3,32,2,1,256,4,1>),   dim3(16384), dim3(256), 0, stream,
                       x, ew1, eb1, A, 128, 128, 128, 64, 64);
    hipLaunchKernelGGL((conv_fp32<4,4,32,64,2,1,256,4,1>),  dim3(8192),  dim3(256), 0, stream,
                       A, ew2, eb2, Bb, 128, 64, 64, 32, 32);
    hipLaunchKernelGGL((conv_fp32<4,4,64,128,2,1,256,4,1>), dim3(4096),  dim3(256), 0, stream,
                       Bb, ew3, eb3, C, 128, 32, 32, 16, 16);
    hipLaunchKernelGGL((conv_fp32<2,2,128,64,1,0,256,4,0>), dim3(2048),  dim3(256), 0, stream,
                       C, ew4, eb4, D, 128, 16, 16, 16, 16);

    // ---- vector quantizer ----
    hipLaunchKernelGGL(zero_loss, dim3(1), dim3(64), 0, stream, outl);
    hipLaunchKernelGGL(vq_kernel, dim3(512), dim3(256), 0, stream,
                       D, emb, E, outi, outl, 0.25f / 2097152.0f);

    // ---- decoder ----
    // dec1: conv_transpose k=2,s=1,'SAME' == conv k=2, pad_low=1
    hipLaunchKernelGGL((conv_fp32<2,2,64,128,1,1,256,4,1>), dim3(4096), dim3(256), 0, stream,
                       E, dw1, db1, C, 128, 16, 16, 16, 16);
    hipLaunchKernelGGL((convt4x4s2<128,64,256,4,1>), dim3(2048,4), dim3(256), 0, stream,
                       C, dw2, db2, Bb, 128, 16, 16);
    hipLaunchKernelGGL((convt4x4s2<64,32,256,4,1>),  dim3(4096,4), dim3(256), 0, stream,
                       Bb, dw3, db3, A, 128, 32, 32);
    hipLaunchKernelGGL((convt4x4s2<32,3,192,2,2>),   dim3(4096,4), dim3(192), 0, stream,
                       A, dw4, db4, outy, 128, 64, 64);
}